// Round 1
// baseline (8948.877 us; speedup 1.0000x reference)
//
#include <hip/hip_runtime.h>
#include <hip/hip_bf16.h>
#include <math.h>

// babyGPT-50m forward: B=2 T=1024 V=50257 C=768 H=12 L=6 D=64
#define Bsz 2
#define Tt 1024
#define Vv 50257
#define Cc 768
#define Hh 12
#define Ll 6
#define Dd 64
#define NTOK (Bsz*Tt)

typedef __attribute__((ext_vector_type(8))) short bf16x8;
typedef __attribute__((ext_vector_type(4))) float f32x4;

static __device__ __forceinline__ unsigned short f2bf(float f){
  unsigned int u = __float_as_uint(f);
  u += 0x7FFF + ((u >> 16) & 1);   // RNE
  return (unsigned short)(u >> 16);
}

// ---------------- embedding: x = tok_emb[idx] + pos_emb ----------------
__global__ void embed_kernel(const int* __restrict__ idx, const float* __restrict__ tok,
                             const float* __restrict__ pos, float* __restrict__ x){
  const int C4 = Cc/4;                         // 192
  int i = blockIdx.x * 256 + threadIdx.x;      // float4 index over NTOK*C4
  if (i >= NTOK*C4) return;
  int tk = i / C4, c4 = i % C4;
  int row = idx[tk];
  int t = tk % Tt;
  float4 a = ((const float4*)tok)[(size_t)row*C4 + c4];
  float4 p = ((const float4*)pos)[(size_t)t*C4 + c4];
  float4 r; r.x=a.x+p.x; r.y=a.y+p.y; r.z=a.z+p.z; r.w=a.w+p.w;
  ((float4*)x)[i] = r;
}

// ---------------- layernorm: one block (256 thr) per token row ----------------
__global__ void ln_kernel(const float* __restrict__ in, const float* __restrict__ g,
                          const float* __restrict__ bt, float* __restrict__ out){
  int row = blockIdx.x, tid = threadIdx.x;
  const float* r = in + (size_t)row*Cc;
  float v0=r[tid], v1=r[tid+256], v2=r[tid+512];
  float s  = v0+v1+v2;
  float s2 = v0*v0+v1*v1+v2*v2;
  #pragma unroll
  for (int off=32; off; off>>=1){ s += __shfl_xor(s,off); s2 += __shfl_xor(s2,off); }
  __shared__ float red[8];
  int wid = tid >> 6;
  if ((tid & 63) == 0){ red[wid]=s; red[4+wid]=s2; }
  __syncthreads();
  float S  = red[0]+red[1]+red[2]+red[3];
  float S2 = red[4]+red[5]+red[6]+red[7];
  float mean = S * (1.0f/Cc);
  float var  = S2 * (1.0f/Cc) - mean*mean;
  float rstd = rsqrtf(var + 1e-5f);
  float* o = out + (size_t)row*Cc;
  o[tid]     = (v0-mean)*rstd*g[tid]     + bt[tid];
  o[tid+256] = (v1-mean)*rstd*g[tid+256] + bt[tid+256];
  o[tid+512] = (v2-mean)*rstd*g[tid+512] + bt[tid+512];
}

// ---------------- GEMM: out[M,N] = act(A[M,K] @ B[K,N] + bias) (+resid) ----------------
// 64x64 tile, 4 waves (2x2), each wave 32x32 via 2x2 mfma_f32_16x16x32_bf16 frags.
// fp32 inputs converted to bf16 (RNE) during LDS staging; fp32 accumulate.
template<bool BIAS, bool RESID, bool GELU>
__global__ __launch_bounds__(256) void gemm_kernel(
    const float* __restrict__ A, const float* __restrict__ Bm,
    const float* __restrict__ bias, const float* __restrict__ resid,
    float* __restrict__ out, int M, int N, int K){
  __shared__ unsigned short As[64][32];   // A[row][k]
  __shared__ unsigned short Bs[64][32];   // B^T: [col][k]
  int m0 = blockIdx.x * 64;               // blockIdx.x = M-tile so consecutive blocks share B-panel
  int n0 = blockIdx.y * 64;
  int tid = threadIdx.x;
  int lane = tid & 63, wid = tid >> 6;
  int wr = wid >> 1, wc = wid & 1;
  int r0 = wr*32, c0 = wc*32;
  int lrow = lane & 15, koff = (lane >> 4) * 8;
  f32x4 acc[2][2] = {};
  for (int k0 = 0; k0 < K; k0 += 32){
    #pragma unroll
    for (int i = 0; i < 2; i++){          // A tile: 512 float4s, 2 per thread
      int e = tid + 256*i;
      int row = e >> 3, c4 = (e & 7) * 4;
      float4 a = *(const float4*)&A[(size_t)(m0+row)*K + k0 + c4];
      ushort4 u; u.x=f2bf(a.x); u.y=f2bf(a.y); u.z=f2bf(a.z); u.w=f2bf(a.w);
      *(ushort4*)&As[row][c4] = u;
    }
    #pragma unroll
    for (int i = 0; i < 8; i++){          // B tile: 2048 scalars, transposed into LDS
      int e = tid + 256*i;
      int kk = e >> 6, n = e & 63;
      int col = n0 + n;
      float v = (col < N) ? Bm[(size_t)(k0+kk)*N + col] : 0.0f;
      Bs[n][kk] = f2bf(v);
    }
    __syncthreads();
    bf16x8 a0 = *(const bf16x8*)&As[r0 + lrow][koff];
    bf16x8 a1 = *(const bf16x8*)&As[r0 + 16 + lrow][koff];
    bf16x8 b0 = *(const bf16x8*)&Bs[c0 + lrow][koff];
    bf16x8 b1 = *(const bf16x8*)&Bs[c0 + 16 + lrow][koff];
    acc[0][0] = __builtin_amdgcn_mfma_f32_16x16x32_bf16(a0,b0,acc[0][0],0,0,0);
    acc[0][1] = __builtin_amdgcn_mfma_f32_16x16x32_bf16(a0,b1,acc[0][1],0,0,0);
    acc[1][0] = __builtin_amdgcn_mfma_f32_16x16x32_bf16(a1,b0,acc[1][0],0,0,0);
    acc[1][1] = __builtin_amdgcn_mfma_f32_16x16x32_bf16(a1,b1,acc[1][1],0,0,0);
    __syncthreads();
  }
  #pragma unroll
  for (int m = 0; m < 2; m++)
  #pragma unroll
  for (int n = 0; n < 2; n++){
    int col = n0 + c0 + n*16 + lrow;
    if (col >= N) continue;
    float bval = BIAS ? bias[col] : 0.0f;
    #pragma unroll
    for (int j = 0; j < 4; j++){
      int row = m0 + r0 + m*16 + (lane>>4)*4 + j;   // D: col=lane&15, row=(lane>>4)*4+j (m89-verified)
      float v = acc[m][n][j] + bval;
      if (GELU) v = 0.5f * v * (1.0f + erff(v * 0.70710678118654752f));
      if (RESID) v += resid[(size_t)row*N + col];
      out[(size_t)row*N + col] = v;
    }
  }
}

// ---------------- attention: one 64-thread block per (b,h,t) query row ----------------
// scores in LDS; softmax over s<=t (identical to -10000-mask + softmax in fp32)
__global__ void attn_kernel(const float* __restrict__ q, const float* __restrict__ k,
                            const float* __restrict__ v, float* __restrict__ y){
  __shared__ float sc[Tt];
  __shared__ float qs[64];
  int w = blockIdx.x;            // ((b*H + h)*T + t)
  int t = w % Tt; int bh = w / Tt; int h = bh % Hh; int b = bh / Hh;
  int lane = threadIdx.x;
  const float scale = 0.125f;    // 1/sqrt(64)
  qs[lane] = q[((size_t)(b*Tt + t))*Cc + h*64 + lane] * scale;
  __syncthreads();
  const float* kbase = k + ((size_t)b*Tt)*Cc + h*64;
  float lmax = -1e30f;
  for (int s = lane; s <= t; s += 64){
    const float4* kr = (const float4*)(kbase + (size_t)s*Cc);
    float acc = 0.f;
    #pragma unroll
    for (int d4 = 0; d4 < 16; d4++){
      float4 kk = kr[d4];
      acc += qs[4*d4]*kk.x + qs[4*d4+1]*kk.y + qs[4*d4+2]*kk.z + qs[4*d4+3]*kk.w;
    }
    sc[s] = acc;
    lmax = fmaxf(lmax, acc);
  }
  #pragma unroll
  for (int off=32; off; off>>=1) lmax = fmaxf(lmax, __shfl_xor(lmax, off));
  float lsum = 0.f;
  for (int s = lane; s <= t; s += 64){
    float p = __expf(sc[s] - lmax);
    sc[s] = p; lsum += p;
  }
  #pragma unroll
  for (int off=32; off; off>>=1) lsum += __shfl_xor(lsum, off);
  float inv = 1.0f / lsum;
  __syncthreads();
  const float* vbase = v + ((size_t)b*Tt)*Cc + h*64 + lane;
  float acc0 = 0.f, acc1 = 0.f;
  int s = 0;
  for (; s + 2 <= t + 1; s += 2){
    acc0 += sc[s]     * vbase[(size_t)s*Cc];
    acc1 += sc[s+1]   * vbase[(size_t)(s+1)*Cc];
  }
  for (; s <= t; s++) acc0 += sc[s] * vbase[(size_t)s*Cc];
  y[((size_t)(b*Tt + t))*Cc + h*64 + lane] = (acc0 + acc1) * inv;
}

// ---------------- orchestration ----------------
extern "C" void kernel_launch(void* const* d_in, const int* in_sizes, int n_in,
                              void* d_out, int out_size, void* d_ws, size_t ws_size,
                              hipStream_t stream){
  const int*   idx  = (const int*)d_in[0];
  const float* tok  = (const float*)d_in[1];
  const float* pos  = (const float*)d_in[2];
  const float* ln1g = (const float*)d_in[3];
  const float* ln1b = (const float*)d_in[4];
  const float* Wq   = (const float*)d_in[5];
  const float* bq   = (const float*)d_in[6];
  const float* Wk   = (const float*)d_in[7];
  const float* bk   = (const float*)d_in[8];
  const float* Wv   = (const float*)d_in[9];
  const float* bv   = (const float*)d_in[10];
  const float* Wp   = (const float*)d_in[11];
  const float* bp   = (const float*)d_in[12];
  const float* ln2g = (const float*)d_in[13];
  const float* ln2b = (const float*)d_in[14];
  const float* Wf1  = (const float*)d_in[15];
  const float* bf1  = (const float*)d_in[16];
  const float* Wf2  = (const float*)d_in[17];
  const float* bf2  = (const float*)d_in[18];
  const float* lnfg = (const float*)d_in[19];
  const float* lnfb = (const float*)d_in[20];
  const float* headW= (const float*)d_in[21];
  float* outp = (float*)d_out;

  // ws layout (fp32): x,h,q,k,v,y each NTOK*C; ff NTOK*4C  -> ~61 MB total
  float* ws = (float*)d_ws;
  const size_t SZ = (size_t)NTOK*Cc;
  float* x  = ws;
  float* h  = x + SZ;
  float* q  = h + SZ;
  float* k  = q + SZ;
  float* v  = k + SZ;
  float* y  = v + SZ;
  float* ff = y + SZ;

  embed_kernel<<<NTOK*(Cc/4)/256, 256, 0, stream>>>(idx, tok, pos, x);

  dim3 g1(NTOK/64, Cc/64);
  dim3 g2(NTOK/64, (4*Cc)/64);
  for (int l = 0; l < Ll; l++){
    ln_kernel<<<NTOK, 256, 0, stream>>>(x, ln1g + l*Cc, ln1b + l*Cc, h);
    gemm_kernel<true,false,false><<<g1, 256, 0, stream>>>(h, Wq + (size_t)l*Cc*Cc, bq + l*Cc, nullptr, q, NTOK, Cc, Cc);
    gemm_kernel<true,false,false><<<g1, 256, 0, stream>>>(h, Wk + (size_t)l*Cc*Cc, bk + l*Cc, nullptr, k, NTOK, Cc, Cc);
    gemm_kernel<true,false,false><<<g1, 256, 0, stream>>>(h, Wv + (size_t)l*Cc*Cc, bv + l*Cc, nullptr, v, NTOK, Cc, Cc);
    attn_kernel<<<Bsz*Hh*Tt, 64, 0, stream>>>(q, k, v, y);
    gemm_kernel<true,true,false><<<g1, 256, 0, stream>>>(y, Wp + (size_t)l*Cc*Cc, bp + l*Cc, x, x, NTOK, Cc, Cc);
    ln_kernel<<<NTOK, 256, 0, stream>>>(x, ln2g + l*Cc, ln2b + l*Cc, h);
    gemm_kernel<true,false,true ><<<g2, 256, 0, stream>>>(h, Wf1 + (size_t)l*Cc*4*Cc, bf1 + (size_t)l*4*Cc, nullptr, ff, NTOK, 4*Cc, Cc);
    gemm_kernel<true,true,false><<<g1, 256, 0, stream>>>(ff, Wf2 + (size_t)l*4*Cc*Cc, bf2 + l*Cc, x, x, NTOK, Cc, 4*Cc);
  }
  ln_kernel<<<NTOK, 256, 0, stream>>>(x, lnfg, lnfb, h);
  dim3 gh(NTOK/64, (Vv + 63)/64);
  gemm_kernel<false,false,false><<<gh, 256, 0, stream>>>(h, headW, nullptr, nullptr, outp, NTOK, Vv, Cc);
}

// Round 2
// 1954.503 us; speedup vs baseline: 4.5786x; 4.5786x over previous
//
#include <hip/hip_runtime.h>
#include <hip/hip_bf16.h>
#include <math.h>

// babyGPT-50m forward: B=2 T=1024 V=50257 C=768 H=12 L=6 D=64
#define Bsz 2
#define Tt 1024
#define Vv 50257
#define Cc 768
#define Hh 12
#define Ll 6
#define NTOK (Bsz*Tt)
#define VPAD 50304

typedef __attribute__((ext_vector_type(8))) short bf16x8;
typedef __attribute__((ext_vector_type(4))) float f32x4;
typedef unsigned short u16;

static __device__ __forceinline__ u16 f2bf(float f){
  unsigned u = __float_as_uint(f);
  u += 0x7FFF + ((u >> 16) & 1);   // RNE
  return (u16)(u >> 16);
}
static __device__ __forceinline__ float bf2f(u16 h){
  return __uint_as_float(((unsigned)h) << 16);
}

// async global->LDS, 16B per lane; LDS dest is wave-uniform base + lane*16
#define GL16(g,l) __builtin_amdgcn_global_load_lds( \
    (const __attribute__((address_space(1))) void*)(g), \
    (__attribute__((address_space(3))) void*)(l), 16, 0, 0)

// ---------------- embedding: x = tok_emb[idx] + pos_emb (fp32) ----------------
__global__ void embed_kernel(const int* __restrict__ idx, const float* __restrict__ tok,
                             const float* __restrict__ pos, float* __restrict__ x){
  const int C4 = Cc/4;
  int i = blockIdx.x * 256 + threadIdx.x;
  if (i >= NTOK*C4) return;
  int tk = i / C4, c4 = i % C4;
  int row = idx[tk];
  int t = tk % Tt;
  float4 a = ((const float4*)tok)[(size_t)row*C4 + c4];
  float4 p = ((const float4*)pos)[(size_t)t*C4 + c4];
  float4 r; r.x=a.x+p.x; r.y=a.y+p.y; r.z=a.z+p.z; r.w=a.w+p.w;
  ((float4*)x)[i] = r;
}

// ---------------- layernorm: fp32 in -> bf16 out ----------------
__global__ void ln_kernel(const float* __restrict__ in, const float* __restrict__ g,
                          const float* __restrict__ bt, u16* __restrict__ out){
  int row = blockIdx.x, tid = threadIdx.x;
  const float* r = in + (size_t)row*Cc;
  float v0=r[tid], v1=r[tid+256], v2=r[tid+512];
  float s  = v0+v1+v2;
  float s2 = v0*v0+v1*v1+v2*v2;
  #pragma unroll
  for (int off=32; off; off>>=1){ s += __shfl_xor(s,off); s2 += __shfl_xor(s2,off); }
  __shared__ float red[8];
  int wid = tid >> 6;
  if ((tid & 63) == 0){ red[wid]=s; red[4+wid]=s2; }
  __syncthreads();
  float S  = red[0]+red[1]+red[2]+red[3];
  float S2 = red[4]+red[5]+red[6]+red[7];
  float mean = S * (1.0f/Cc);
  float var  = S2 * (1.0f/Cc) - mean*mean;
  float rstd = rsqrtf(var + 1e-5f);
  u16* o = out + (size_t)row*Cc;
  o[tid]     = f2bf((v0-mean)*rstd*g[tid]     + bt[tid]);
  o[tid+256] = f2bf((v1-mean)*rstd*g[tid+256] + bt[tid+256]);
  o[tid+512] = f2bf((v2-mean)*rstd*g[tid+512] + bt[tid+512]);
}

// ---------------- weight transpose+convert: fp32 [K][N] -> bf16 [Npad][K] ----------------
__global__ void wtrans_kernel(const float* __restrict__ in, u16* __restrict__ out,
                              int K, int N, int Npad){
  __shared__ float t[32][33];
  int n0 = blockIdx.x*32, k0 = blockIdx.y*32;
  int tx = threadIdx.x, ty = threadIdx.y;   // block (32,8)
  #pragma unroll
  for (int i=0;i<4;i++){
    int k = k0+ty+i*8, n = n0+tx;
    t[ty+i*8][tx] = (n < N) ? in[(size_t)k*N + n] : 0.f;
  }
  __syncthreads();
  #pragma unroll
  for (int i=0;i<4;i++){
    int n = n0+ty+i*8, k = k0+tx;
    if (n < Npad) out[(size_t)n*K + k] = f2bf(t[tx][ty+i*8]);
  }
}

// ---------------- v-part of qkv -> vT[b,h][d][t] (bf16) ----------------
__global__ void vtrans_kernel(const u16* __restrict__ qkv, u16* __restrict__ vT){
  __shared__ u16 s[32][33];
  int bh = blockIdx.z; int b = bh/Hh, h = bh - b*Hh;
  int t0 = blockIdx.x*32, d0 = blockIdx.y*32;
  int tx=threadIdx.x, ty=threadIdx.y;       // block (32,8)
  #pragma unroll
  for (int i=0;i<4;i++)
    s[ty+i*8][tx] = qkv[(size_t)(b*Tt + t0+ty+i*8)*2304 + 1536 + h*64 + d0 + tx];
  __syncthreads();
  #pragma unroll
  for (int i=0;i<4;i++)
    vT[((size_t)bh*64 + d0+ty+i*8)*Tt + t0 + tx] = s[tx][ty+i*8];
}

// ---------------- bias concat [L][2304] ----------------
__global__ void bconcat_kernel(const float* __restrict__ bq, const float* __restrict__ bk,
                               const float* __restrict__ bv, float* __restrict__ o){
  int i = blockIdx.x*256 + threadIdx.x;
  if (i >= Ll*2304) return;
  int l = i/2304, j = i - l*2304;
  o[i] = (j < 768) ? bq[l*768+j] : (j < 1536) ? bk[l*768+j-768] : bv[l*768+j-1536];
}

// ---------------- causal row softmax over S (bf16, in place, normalized) ----------------
__global__ __launch_bounds__(256) void softmax_kernel(u16* __restrict__ S){
  __shared__ float red[8];
  int t = blockIdx.x & (Tt-1);
  u16* row = S + (size_t)blockIdx.x*Tt;
  int tid = threadIdx.x;
  int i0 = tid*4;
  ushort4 u = *(const ushort4*)&row[i0];
  float v0 = (i0   <= t) ? bf2f(u.x)*0.125f : -1e30f;
  float v1 = (i0+1 <= t) ? bf2f(u.y)*0.125f : -1e30f;
  float v2 = (i0+2 <= t) ? bf2f(u.z)*0.125f : -1e30f;
  float v3 = (i0+3 <= t) ? bf2f(u.w)*0.125f : -1e30f;
  float m = fmaxf(fmaxf(v0,v1), fmaxf(v2,v3));
  #pragma unroll
  for (int off=32; off; off>>=1) m = fmaxf(m, __shfl_xor(m, off));
  int wid = tid >> 6;
  if ((tid&63)==0) red[wid] = m;
  __syncthreads();
  m = fmaxf(fmaxf(red[0],red[1]), fmaxf(red[2],red[3]));
  float p0 = __expf(v0-m), p1 = __expf(v1-m), p2 = __expf(v2-m), p3 = __expf(v3-m);
  float s = p0+p1+p2+p3;
  #pragma unroll
  for (int off=32; off; off>>=1) s += __shfl_xor(s, off);
  if ((tid&63)==0) red[4+wid] = s;
  __syncthreads();
  float inv = 1.0f / (red[4]+red[5]+red[6]+red[7]);
  ushort4 w;
  w.x = f2bf(p0*inv); w.y = f2bf(p1*inv); w.z = f2bf(p2*inv); w.w = f2bf(p3*inv);
  *(ushort4*)&row[i0] = w;
}

// ---------------- MFMA GEMM, m97 structure: 128xBN tile, BK=32, global_load_lds(16) ----
// A bf16 [*, lda] k-contiguous rows; B bf16 "B^T" [*, ldb] k-contiguous rows.
// MODE 0: plain (z=0). MODE 1: S=QK^T from qkv (batched b,h; skip above-diagonal).
// MODE 2: Y=P.V from S and vT (batched; causal K bound; token-major C).
template<int MODE, int BN, bool BIAS, bool RESID, bool GELU, bool OUTBF>
__global__ __launch_bounds__(256) void mm_kernel(
    const u16* __restrict__ A, const u16* __restrict__ Bm,
    const float* __restrict__ bias, const float* __restrict__ resid,
    void* __restrict__ out, int N, int K, int lda, int ldb, int ldc)
{
  constexpr int FN = (BN==128) ? 4 : 2;
  __shared__ u16 As[128*32];
  __shared__ u16 Bs[BN*32];
  int m0 = blockIdx.x*128, n0 = blockIdx.y*BN;
  int z = blockIdx.z;
  size_t Ab=0, Bb=0, Cb=0; int kend = K;
  if constexpr (MODE==1){
    if (n0 > m0) return;                       // fully-masked causal block
    int b = z/Hh, h = z - b*Hh;
    Ab = (size_t)b*Tt*2304 + h*64;             // q rows
    Bb = Ab + 768;                             // k rows
    Cb = (size_t)z*Tt*Tt;
  } else if constexpr (MODE==2){
    Ab = (size_t)z*Tt*Tt;                      // P rows
    Bb = (size_t)z*64*Tt;                      // vT rows
    int b = z/Hh, h = z - b*Hh;
    Cb = (size_t)b*Tt*Cc + h*64;               // y token-major
    kend = (m0+128 < K) ? m0+128 : K;          // causal: P[t][s]=0 for s>t
  }
  int tid = threadIdx.x, lane = tid & 63, wid = tid >> 6;
  int wr = wid >> 1, wc = wid & 1;
  int r0 = wr*64, c0 = wc*(BN/2);
  int lrow = lane & 15, koff = (lane >> 4)*8;
  int sr = lane >> 2, sk = (lane & 3)*8;       // staging: lane covers row sr, 8 k's at sk
  const u16* Ap = A + Ab + (size_t)(m0 + wid*32 + sr)*lda + sk;
  const u16* Bp = (BN==128) ? Bm + Bb + (size_t)(n0 + wid*32 + sr)*ldb + sk
                            : Bm + Bb + (size_t)(n0 + wid*16 + sr)*ldb + sk;
  u16* Al = As + wid*1024;                     // wave-uniform LDS bases
  u16* Bl = (BN==128) ? Bs + wid*1024 : Bs + wid*512;
  f32x4 acc[4][FN] = {};
  for (int k0 = 0; k0 < kend; k0 += 32){
    GL16(Ap + k0, Al);
    GL16(Ap + k0 + (size_t)16*lda, Al + 512);
    if constexpr (BN==128){
      GL16(Bp + k0, Bl);
      GL16(Bp + k0 + (size_t)16*ldb, Bl + 512);
    } else {
      GL16(Bp + k0, Bl);
    }
    __syncthreads();                            // drains vmcnt before barrier
    bf16x8 af[4], bfr[FN];
    #pragma unroll
    for (int m=0;m<4;m++) af[m] = *(const bf16x8*)&As[(r0 + m*16 + lrow)*32 + koff];
    #pragma unroll
    for (int n=0;n<FN;n++) bfr[n] = *(const bf16x8*)&Bs[(c0 + n*16 + lrow)*32 + koff];
    #pragma unroll
    for (int m=0;m<4;m++)
      #pragma unroll
      for (int n=0;n<FN;n++)
        acc[m][n] = __builtin_amdgcn_mfma_f32_16x16x32_bf16(af[m], bfr[n], acc[m][n], 0,0,0);
    __syncthreads();
  }
  #pragma unroll
  for (int m=0;m<4;m++){
    int grb = m0 + r0 + m*16 + (lane>>4)*4;     // D: col=lane&15, row=(lane>>4)*4+j
    #pragma unroll
    for (int n=0;n<FN;n++){
      int gc = n0 + c0 + n*16 + lrow;
      if (gc >= N) continue;
      float bv_ = BIAS ? bias[gc] : 0.f;
      #pragma unroll
      for (int j=0;j<4;j++){
        float v = acc[m][n][j] + bv_;
        if (GELU) v = 0.5f*v*(1.f + erff(v*0.70710678118654752f));
        size_t oi = Cb + (size_t)(grb+j)*ldc + gc;
        if (RESID) v += resid[oi];
        if (OUTBF) ((u16*)out)[oi] = f2bf(v);
        else       ((float*)out)[oi] = v;
      }
    }
  }
}

// ---------------- orchestration ----------------
extern "C" void kernel_launch(void* const* d_in, const int* in_sizes, int n_in,
                              void* d_out, int out_size, void* d_ws, size_t ws_size,
                              hipStream_t stream){
  const int*   idx  = (const int*)d_in[0];
  const float* tok  = (const float*)d_in[1];
  const float* pos  = (const float*)d_in[2];
  const float* ln1g = (const float*)d_in[3];
  const float* ln1b = (const float*)d_in[4];
  const float* Wq   = (const float*)d_in[5];
  const float* bq   = (const float*)d_in[6];
  const float* Wk   = (const float*)d_in[7];
  const float* bk   = (const float*)d_in[8];
  const float* Wv   = (const float*)d_in[9];
  const float* bv   = (const float*)d_in[10];
  const float* Wp   = (const float*)d_in[11];
  const float* bp   = (const float*)d_in[12];
  const float* ln2g = (const float*)d_in[13];
  const float* ln2b = (const float*)d_in[14];
  const float* Wf1  = (const float*)d_in[15];
  const float* bf1  = (const float*)d_in[16];
  const float* Wf2  = (const float*)d_in[17];
  const float* bf2  = (const float*)d_in[18];
  const float* lnfg = (const float*)d_in[19];
  const float* lnfb = (const float*)d_in[20];
  const float* headW= (const float*)d_in[21];
  float* outp = (float*)d_out;

  // workspace layout (~250 MB)
  char* w = (char*)d_ws;
  u16* wqkvT = (u16*)w;  w += (size_t)Ll*2304*768*2;   // [L][2304][768]
  u16* wpT   = (u16*)w;  w += (size_t)Ll*768*768*2;    // [L][768][768]
  u16* wf1T  = (u16*)w;  w += (size_t)Ll*3072*768*2;   // [L][3072][768]
  u16* wf2T  = (u16*)w;  w += (size_t)Ll*768*3072*2;   // [L][768][3072]
  u16* headT = (u16*)w;  w += (size_t)VPAD*768*2;      // [50304][768], zero-padded
  float* bqkv= (float*)w;w += (size_t)Ll*2304*4;
  float* x   = (float*)w;w += (size_t)NTOK*Cc*4;       // fp32 residual stream
  u16* h     = (u16*)w;  w += (size_t)NTOK*Cc*2;       // LN output (bf16)
  u16* qkv   = (u16*)w;  w += (size_t)NTOK*2304*2;
  u16* vT    = (u16*)w;  w += (size_t)Bsz*Hh*64*Tt*2;
  u16* S     = (u16*)w;  w += (size_t)Bsz*Hh*Tt*Tt*2;  // scores / probs (in place)
  u16* y     = (u16*)w;  w += (size_t)NTOK*Cc*2;
  u16* ff    = (u16*)w;  w += (size_t)NTOK*4*Cc*2;

  dim3 tb(32,8);
  for (int l=0;l<Ll;l++){
    wtrans_kernel<<<dim3(24,24), tb, 0, stream>>>(Wq+(size_t)l*Cc*Cc, wqkvT+(size_t)l*2304*768,          768, 768, 768);
    wtrans_kernel<<<dim3(24,24), tb, 0, stream>>>(Wk+(size_t)l*Cc*Cc, wqkvT+(size_t)l*2304*768+768*768,  768, 768, 768);
    wtrans_kernel<<<dim3(24,24), tb, 0, stream>>>(Wv+(size_t)l*Cc*Cc, wqkvT+(size_t)l*2304*768+1536*768, 768, 768, 768);
    wtrans_kernel<<<dim3(24,24), tb, 0, stream>>>(Wp+(size_t)l*Cc*Cc, wpT+(size_t)l*768*768,             768, 768, 768);
    wtrans_kernel<<<dim3(96,24), tb, 0, stream>>>(Wf1+(size_t)l*Cc*4*Cc, wf1T+(size_t)l*3072*768,        768, 3072, 3072);
    wtrans_kernel<<<dim3(24,96), tb, 0, stream>>>(Wf2+(size_t)l*4*Cc*Cc, wf2T+(size_t)l*768*3072,        3072, 768, 768);
  }
  wtrans_kernel<<<dim3(VPAD/32,24), tb, 0, stream>>>(headW, headT, 768, Vv, VPAD);
  bconcat_kernel<<<(Ll*2304+255)/256, 256, 0, stream>>>(bq, bk, bv, bqkv);

  embed_kernel<<<NTOK*(Cc/4)/256, 256, 0, stream>>>(idx, tok, pos, x);

  for (int l=0;l<Ll;l++){
    ln_kernel<<<NTOK, 256, 0, stream>>>(x, ln1g+l*Cc, ln1b+l*Cc, h);
    // qkv = h @ WqkvT + b   [2048][2304] bf16
    mm_kernel<0,128,true,false,false,true><<<dim3(16,18,1), 256, 0, stream>>>(
        h, wqkvT+(size_t)l*2304*768, bqkv+l*2304, nullptr, qkv, 2304, 768, 768, 768, 2304);
    vtrans_kernel<<<dim3(32,2,Bsz*Hh), tb, 0, stream>>>(qkv, vT);
    // S = q k^T (batched over b,h; causal blocks skipped)
    mm_kernel<1,128,false,false,false,true><<<dim3(8,8,Bsz*Hh), 256, 0, stream>>>(
        qkv, qkv, nullptr, nullptr, S, 1024, 64, 2304, 2304, 1024);
    softmax_kernel<<<Bsz*Hh*Tt, 256, 0, stream>>>(S);
    // y = P v  (batched; token-major bf16 out)
    mm_kernel<2,64,false,false,false,true><<<dim3(8,1,Bsz*Hh), 256, 0, stream>>>(
        S, vT, nullptr, nullptr, y, 64, 1024, 1024, 1024, 768);
    // x += y @ WpT + bp   (fp32 out, residual)
    mm_kernel<0,128,true,true,false,false><<<dim3(16,6,1), 256, 0, stream>>>(
        y, wpT+(size_t)l*768*768, bp+l*Cc, x, x, 768, 768, 768, 768, 768);
    ln_kernel<<<NTOK, 256, 0, stream>>>(x, ln2g+l*Cc, ln2b+l*Cc, h);
    // ff = gelu(h @ Wf1T + bf1)  bf16
    mm_kernel<0,128,true,false,true,true><<<dim3(16,24,1), 256, 0, stream>>>(
        h, wf1T+(size_t)l*3072*768, bf1+(size_t)l*4*Cc, nullptr, ff, 3072, 768, 768, 768, 3072);
    // x += ff @ Wf2T + bf2
    mm_kernel<0,128,true,true,false,false><<<dim3(16,6,1), 256, 0, stream>>>(
        ff, wf2T+(size_t)l*768*3072, bf2+l*Cc, x, x, 768, 3072, 3072, 3072, 768);
  }
  ln_kernel<<<NTOK, 256, 0, stream>>>(x, lnfg, lnfb, h);
  mm_kernel<0,128,false,false,false,false><<<dim3(16,VPAD/128,1), 256, 0, stream>>>(
      h, headT, nullptr, nullptr, outp, Vv, 768, 768, 768, Vv);
}